// Round 3
// baseline (522.247 us; speedup 1.0000x reference)
//
#include <hip/hip_runtime.h>
#include <stdint.h>

typedef __attribute__((ext_vector_type(8))) short short8;
typedef __attribute__((ext_vector_type(4))) float f32x4;

#define MFMA(A, B, C) __builtin_amdgcn_mfma_f32_16x16x32_bf16(A, B, C, 0, 0, 0)

__device__ inline void split_trunc(float f, short& hi, short& lo) {
  uint32_t u = __float_as_uint(f);
  hi = (short)(u >> 16);
  float r = f - __uint_as_float(u & 0xffff0000u);
  lo = (short)(__float_as_uint(r) >> 16);
}

__device__ inline void gload16(const short* g, short* l) {
  __builtin_amdgcn_global_load_lds(
      (const __attribute__((address_space(1))) void*)g,
      (__attribute__((address_space(3))) void*)l, 16, 0, 0);
}

// ---------- prep kernels ----------

// x f32 -> xhi/xlo bf16 trunc-split (8 elems/thread)
__global__ void split_x_kernel(const float* __restrict__ x, short* __restrict__ hi,
                               short* __restrict__ lo) {
  int t = blockIdx.x * 256 + threadIdx.x;   // 524288 chunks
  float4 v0 = *(const float4*)&x[(size_t)t * 8];
  float4 v1 = *(const float4*)&x[(size_t)t * 8 + 4];
  float buf[8] = {v0.x, v0.y, v0.z, v0.w, v1.x, v1.y, v1.z, v1.w};
  short8 h, l;
#pragma unroll
  for (int i = 0; i < 8; ++i) { short a, b; split_trunc(buf[i], a, b); h[i] = a; l[i] = b; }
  *(short8*)&hi[(size_t)t * 8] = h;
  *(short8*)&lo[(size_t)t * 8] = l;
}

// sr_w (O=512,I=512,2,2) -> WcT[o][kk=seg*512+c] trunc-split
__global__ void build_wct_split(const float* __restrict__ sr_w,
                                short* __restrict__ hi, short* __restrict__ lo) {
  int t = blockIdx.x * 256 + threadIdx.x;   // 512*2048
  int kk = t & 2047, o = t >> 11;
  float v = sr_w[(size_t)o * 2048 + ((kk & 511) << 2) + (kk >> 9)];
  short a, b; split_trunc(v, a, b);
  hi[t] = a; lo[t] = b;
}

// f32 [K][N] -> bf16 hi/lo [N][K] trunc-split
__global__ __launch_bounds__(256) void transpose_split_kernel(
    const float* __restrict__ in, short* __restrict__ ohi, short* __restrict__ olo,
    int K, int N) {
  __shared__ float tile[32][33];
  const int bx = blockIdx.x, by = blockIdx.y;
  const int tx = threadIdx.x & 31, ty = threadIdx.x >> 5;
#pragma unroll
  for (int i = 0; i < 4; ++i)
    tile[ty + i * 8][tx] = in[(size_t)(by * 32 + ty + i * 8) * N + bx * 32 + tx];
  __syncthreads();
#pragma unroll
  for (int i = 0; i < 4; ++i) {
    int n = bx * 32 + ty + i * 8;
    float v = tile[tx][ty + i * 8];
    short a, b; split_trunc(v, a, b);
    size_t idx = (size_t)n * K + by * 32 + tx;
    ohi[idx] = a; olo[idx] = b;
  }
}

// LayerNorm over 512; input = 4 k-split partials (stride 2048*512); out bf16 hi/lo
__global__ __launch_bounds__(256) void ln_split_kernel(
    const float* __restrict__ X, const float* __restrict__ g,
    const float* __restrict__ bta, short* __restrict__ hi, short* __restrict__ lo) {
  const int row = blockIdx.x, t = threadIdx.x;
  size_t idx = (size_t)row * 512 + t * 2;
  const size_t PS = (size_t)2048 * 512;
  float2 a0 = *(const float2*)&X[idx];
  float2 a1 = *(const float2*)&X[idx + PS];
  float2 a2 = *(const float2*)&X[idx + 2 * PS];
  float2 a3 = *(const float2*)&X[idx + 3 * PS];
  float x0 = a0.x + a1.x + a2.x + a3.x;
  float x1 = a0.y + a1.y + a2.y + a3.y;
  float s = x0 + x1, sq = x0 * x0 + x1 * x1;
#pragma unroll
  for (int off = 1; off < 64; off <<= 1) {
    s += __shfl_xor(s, off);
    sq += __shfl_xor(sq, off);
  }
  __shared__ float rs[4], rq[4];
  int wid = t >> 6;
  if ((t & 63) == 0) { rs[wid] = s; rq[wid] = sq; }
  __syncthreads();
  s = rs[0] + rs[1] + rs[2] + rs[3];
  sq = rq[0] + rq[1] + rq[2] + rq[3];
  float mu = s * (1.f / 512), var = sq * (1.f / 512) - mu * mu;
  float inv = rsqrtf(var + 1e-5f);
  float2 gg = *(const float2*)&g[t * 2], bb = *(const float2*)&bta[t * 2];
  float o0 = (x0 - mu) * inv * gg.x + bb.x;
  float o1 = (x1 - mu) * inv * gg.y + bb.y;
  short h0, l0, h1, l1;
  split_trunc(o0, h0, l0);
  split_trunc(o1, h1, l1);
  *(uint32_t*)&hi[idx] = (uint32_t)(uint16_t)h0 | ((uint32_t)(uint16_t)h1 << 16);
  *(uint32_t*)&lo[idx] = (uint32_t)(uint16_t)l0 | ((uint32_t)(uint16_t)l1 << 16);
}

// KV (2 partials) K-half -> Khi/Klo [b][2048m][64d]
__global__ void build_k_split(const float* __restrict__ KV1, const float* __restrict__ KV2,
                              short* __restrict__ khi, short* __restrict__ klo) {
  int t = blockIdx.x * 256 + threadIdx.x;   // 8*2048*64
  int b = t >> 17, i = t & 131071;
  size_t idx = ((size_t)b * 256 + (i >> 9)) * 1024 + (i & 511);
  float v = KV1[idx] + KV2[idx];
  short a, c; split_trunc(v, a, c);
  khi[t] = a; klo[t] = c;
}

// KV (2 partials) V-half -> VT bf16 (RNE) [b][64d][2048m]
__global__ void build_vt_kernel(const float* __restrict__ KV1, const float* __restrict__ KV2,
                                short* __restrict__ vt) {
  int t = blockIdx.x * 256 + threadIdx.x;   // 8*64*2048
  int b = t >> 17, i = t & 131071;
  int d = i >> 11, m = i & 2047;
  size_t idx = ((size_t)b * 256 + (m >> 3)) * 1024 + 512 + (m & 7) * 64 + d;
  float v = KV1[idx] + KV2[idx];
  uint32_t u = __float_as_uint(v);
  vt[t] = (short)((u + 0x7FFFu + ((u >> 16) & 1u)) >> 16);
}

// ---------- bf16x3 GEMM (global_load_lds staging; optional patch-gather A) ----------
template <bool GATHER>
__global__ __launch_bounds__(256) void gemm_x3(
    const short* __restrict__ Ahi, const short* __restrict__ Alo,
    const short* __restrict__ BThi, const short* __restrict__ BTlo,
    const float* __restrict__ bias, float* __restrict__ C,
    int M, int N, int lda, int ldb, int klen) {
  __shared__ short lds[4][4][128][8];   // [Ah,Al,Bh,Bl][kg][row][8] = 32KB
  const int tid = threadIdx.x, lane = tid & 63, wave = tid >> 6;
  const int wr = (wave >> 1) * 64, wc = (wave & 1) * 64;
  const int row0 = blockIdx.x * 128, col0 = blockIdx.y * 128;
  const int kz = blockIdx.z * klen;
  float* Cz = C + (size_t)blockIdx.z * M * N;
  const bool dobias = (blockIdx.z == 0);
  f32x4 acc[4][4] = {};
  const int sm = tid & 127, khalf = tid >> 7;

  for (int k0 = kz; k0 < kz + klen; k0 += 32) {
    __syncthreads();
#pragma unroll
    for (int c = 0; c < 2; ++c) {
      int kg = khalf * 2 + c;
      size_t ao;
      if (GATHER) {
        int row = row0 + sm;
        int bi = row >> 8, p = row & 255;
        int col = k0 + kg * 8;
        int seg = col >> 9, cc = col & 511;
        int n = (2 * (p >> 4) + (seg >> 1)) * 32 + 2 * (p & 15) + (seg & 1);
        ao = ((size_t)bi * 1024 + n) * 512 + cc;
      } else {
        ao = (size_t)(row0 + sm) * lda + k0 + kg * 8;
      }
      size_t bo = (size_t)(col0 + sm) * ldb + k0 + kg * 8;
      gload16(&Ahi[ao], &lds[0][kg][sm][0]);
      gload16(&Alo[ao], &lds[1][kg][sm][0]);
      gload16(&BThi[bo], &lds[2][kg][sm][0]);
      gload16(&BTlo[bo], &lds[3][kg][sm][0]);
    }
    __syncthreads();
    const int kg = lane >> 4;
    short8 ah[4], al[4], bh[4], bl[4];
#pragma unroll
    for (int i = 0; i < 4; ++i) {
      ah[i] = *(const short8*)&lds[0][kg][wr + i * 16 + (lane & 15)][0];
      al[i] = *(const short8*)&lds[1][kg][wr + i * 16 + (lane & 15)][0];
      bh[i] = *(const short8*)&lds[2][kg][wc + i * 16 + (lane & 15)][0];
      bl[i] = *(const short8*)&lds[3][kg][wc + i * 16 + (lane & 15)][0];
    }
#pragma unroll
    for (int i = 0; i < 4; ++i)
#pragma unroll
      for (int j = 0; j < 4; ++j) {
        acc[i][j] = MFMA(ah[i], bh[j], acc[i][j]);
        acc[i][j] = MFMA(al[i], bh[j], acc[i][j]);
        acc[i][j] = MFMA(ah[i], bl[j], acc[i][j]);
      }
  }
#pragma unroll
  for (int i = 0; i < 4; ++i)
#pragma unroll
    for (int j = 0; j < 4; ++j) {
      int colb = col0 + wc + j * 16 + (lane & 15);
      float bs = dobias ? bias[colb] : 0.f;
#pragma unroll
      for (int r = 0; r < 4; ++r) {
        int row = row0 + wr + i * 16 + (lane >> 4) * 4 + r;
        Cz[(size_t)row * N + colb] = acc[i][j][r] + bs;
      }
    }
}

// ---------- barrier-free MFMA flash attention ----------
// grid (16, 8, 8), 256 thr; swapped QK^T (S^T), defer-max, per-wave P LDS bounce
__global__ __launch_bounds__(256) void attn_kernel(
    const float* __restrict__ Q, const short* __restrict__ Khi,
    const short* __restrict__ Klo, const short* __restrict__ VT,
    short* __restrict__ Ohi, short* __restrict__ Olo) {
  __shared__ short Ps[4][2][1024];   // [wave][hi/lo][q16*m64], b64-swizzled, 16KB
  const int tid = threadIdx.x, lane = tid & 63, wave = tid >> 6;
  const int g = lane >> 4, qi = lane & 15;
  const int h = blockIdx.y, b = blockIdx.z;
  const int n0 = blockIdx.x * 64 + wave * 16;

  // Q frags (B-operand): lane holds Q[q=qi][d=(ks*4+g)*8 ..+8] * 0.125, trunc-split
  short8 qh[2], ql[2];
  {
    const float* Qr = Q + ((size_t)b * 1024 + n0 + qi) * 512 + h * 64;
#pragma unroll
    for (int ks = 0; ks < 2; ++ks) {
      int dg = ks * 4 + g;
      float4 v0 = *(const float4*)(Qr + dg * 8);
      float4 v1 = *(const float4*)(Qr + dg * 8 + 4);
      float buf[8] = {v0.x, v0.y, v0.z, v0.w, v1.x, v1.y, v1.z, v1.w};
#pragma unroll
      for (int j = 0; j < 8; ++j) {
        short a, c; split_trunc(buf[j] * 0.125f, a, c);
        qh[ks][j] = a; ql[ks][j] = c;
      }
    }
  }
  float m_run = 0.f, l_run = 0.f;
  f32x4 oacc[4] = {};
  const short* Kh = Khi + (size_t)b * 2048 * 64;
  const short* Kl = Klo + (size_t)b * 2048 * 64;
  const short* Vb = VT + (size_t)b * 64 * 2048;
  const int swz = (qi & 7) << 1;

  for (int t = 0; t < 32; ++t) {
    const int m0 = t * 64;
    // QK^T swapped: S^T[m][q], x3 split, K direct from L2
    f32x4 s[4] = {};
#pragma unroll
    for (int mf = 0; mf < 4; ++mf) {
      const size_t rb = (size_t)(m0 + mf * 16 + qi) * 64 + g * 8;
      short8 kh0 = *(const short8*)&Kh[rb];
      short8 kl0 = *(const short8*)&Kl[rb];
      short8 kh1 = *(const short8*)&Kh[rb + 32];
      short8 kl1 = *(const short8*)&Kl[rb + 32];
      s[mf] = MFMA(kh0, qh[0], s[mf]);
      s[mf] = MFMA(kl0, qh[0], s[mf]);
      s[mf] = MFMA(kh0, ql[0], s[mf]);
      s[mf] = MFMA(kh1, qh[1], s[mf]);
      s[mf] = MFMA(kl1, qh[1], s[mf]);
      s[mf] = MFMA(kh1, ql[1], s[mf]);
    }
    // defer-max online softmax (m_run wave-global, rarely updated)
    float lmax = s[0][0];
#pragma unroll
    for (int mf = 0; mf < 4; ++mf)
#pragma unroll
      for (int r = 0; r < 4; ++r) lmax = fmaxf(lmax, s[mf][r]);
    if (!__all(lmax <= m_run + 30.f)) {
      float mx = lmax;
#pragma unroll
      for (int off = 1; off < 64; off <<= 1) mx = fmaxf(mx, __shfl_xor(mx, off));
      float cf = __expf(m_run - mx);
      l_run *= cf;
#pragma unroll
      for (int df = 0; df < 4; ++df) oacc[df] *= cf;
      m_run = mx;
    }
    float lsum = 0.f;
#pragma unroll
    for (int mf = 0; mf < 4; ++mf)
#pragma unroll
      for (int r = 0; r < 4; ++r) {
        float p = __expf(s[mf][r] - m_run);
        s[mf][r] = p;
        lsum += p;
      }
    lsum += __shfl_xor(lsum, 16);
    lsum += __shfl_xor(lsum, 32);
    l_run += lsum;
    // pack P (trunc hi + residual lo) -> per-wave LDS, b64-swizzled
#pragma unroll
    for (int mf = 0; mf < 4; ++mf) {
      uint32_t u0 = __float_as_uint(s[mf][0]);
      uint32_t u1 = __float_as_uint(s[mf][1]);
      uint32_t u2 = __float_as_uint(s[mf][2]);
      uint32_t u3 = __float_as_uint(s[mf][3]);
      uint2 hp, lp;
      hp.x = (u0 >> 16) | (u1 & 0xffff0000u);
      hp.y = (u2 >> 16) | (u3 & 0xffff0000u);
      float r0 = s[mf][0] - __uint_as_float(u0 & 0xffff0000u);
      float r1 = s[mf][1] - __uint_as_float(u1 & 0xffff0000u);
      float r2 = s[mf][2] - __uint_as_float(u2 & 0xffff0000u);
      float r3 = s[mf][3] - __uint_as_float(u3 & 0xffff0000u);
      lp.x = (__float_as_uint(r0) >> 16) | (__float_as_uint(r1) & 0xffff0000u);
      lp.y = (__float_as_uint(r2) >> 16) | (__float_as_uint(r3) & 0xffff0000u);
      int uw = ((mf * 4 + g) ^ swz) << 2;
      *(uint2*)&Ps[wave][0][qi * 64 + uw] = hp;
      *(uint2*)&Ps[wave][1][qi * 64 + uw] = lp;
    }
    // PV: out^T[d][q] += V^T frag x P frag (x2: hi+lo)
#pragma unroll
    for (int ks2 = 0; ks2 < 2; ++ks2) {
      int ur = ((ks2 * 8 + g * 2) ^ swz) << 2;
      short8 pa = *(const short8*)&Ps[wave][0][qi * 64 + ur];
      short8 pl = *(const short8*)&Ps[wave][1][qi * 64 + ur];
#pragma unroll
      for (int df = 0; df < 4; ++df) {
        short8 vb = *(const short8*)&Vb[(size_t)(df * 16 + qi) * 2048 + m0 + ks2 * 32 + g * 8];
        oacc[df] = MFMA(vb, pa, oacc[df]);
        oacc[df] = MFMA(vb, pl, oacc[df]);
      }
    }
  }
  // epilogue: divide by l, trunc-split, packed 8B stores
  float linv = 1.f / l_run;
  size_t obase = ((size_t)b * 1024 + n0 + qi) * 512 + h * 64;
#pragma unroll
  for (int df = 0; df < 4; ++df) {
    float o0 = oacc[df][0] * linv, o1 = oacc[df][1] * linv;
    float o2 = oacc[df][2] * linv, o3 = oacc[df][3] * linv;
    uint32_t u0 = __float_as_uint(o0), u1 = __float_as_uint(o1);
    uint32_t u2 = __float_as_uint(o2), u3 = __float_as_uint(o3);
    uint2 hp, lp;
    hp.x = (u0 >> 16) | (u1 & 0xffff0000u);
    hp.y = (u2 >> 16) | (u3 & 0xffff0000u);
    float r0 = o0 - __uint_as_float(u0 & 0xffff0000u);
    float r1 = o1 - __uint_as_float(u1 & 0xffff0000u);
    float r2 = o2 - __uint_as_float(u2 & 0xffff0000u);
    float r3 = o3 - __uint_as_float(u3 & 0xffff0000u);
    lp.x = (__float_as_uint(r0) >> 16) | (__float_as_uint(r1) & 0xffff0000u);
    lp.y = (__float_as_uint(r2) >> 16) | (__float_as_uint(r3) & 0xffff0000u);
    *(uint2*)&Ohi[obase + df * 16 + g * 4] = hp;
    *(uint2*)&Olo[obase + df * 16 + g * 4] = lp;
  }
}

// ---------- launcher ----------
extern "C" void kernel_launch(void* const* d_in, const int* in_sizes, int n_in,
                              void* d_out, int out_size, void* d_ws, size_t ws_size,
                              hipStream_t stream) {
  const float* x      = (const float*)d_in[0];
  const float* q_w    = (const float*)d_in[3];
  const float* q_b    = (const float*)d_in[4];
  const float* kv_w   = (const float*)d_in[5];
  const float* kv_b   = (const float*)d_in[6];
  const float* sr_w   = (const float*)d_in[7];
  const float* sr_b   = (const float*)d_in[8];
  const float* ln_g   = (const float*)d_in[9];
  const float* ln_b   = (const float*)d_in[10];
  const float* proj_w = (const float*)d_in[11];
  const float* proj_b = (const float*)d_in[12];

  char* W = (char*)d_ws;
  const size_t MB = 1024 * 1024;
  short* xhi  = (short*)(W);             // 0-8
  short* xlo  = (short*)(W + 8 * MB);    // 8-16
  short* WcThi = (short*)(W + 16 * MB);  // 16-18
  short* WcTlo = (short*)(W + 18 * MB);  // 18-20
  float* Cbuf = (float*)(W + 20 * MB);   // 20-36 (4 partials x 4MB)
  short* LNhi = (short*)(W + 36 * MB);   // 36-38
  short* LNlo = (short*)(W + 38 * MB);   // 38-40
  short* wThi = (short*)(W + 40 * MB);   // 40-41
  short* wTlo = (short*)(W + 41 * MB);   // 41-42
  float* KVp  = (float*)(W + 20 * MB);   // 20-36 (2 partials x 8MB; Cbuf dead)
  short* Khi  = (short*)(W + 36 * MB);   // 36-38 (LN dead)
  short* Klo  = (short*)(W + 38 * MB);   // 38-40
  short* VTb  = (short*)(W + 16 * MB);   // 16-18 (WcT dead)
  float* Qbuf = (float*)(W + 20 * MB);   // 20-36 (KVp dead)
  short* Ohi  = (short*)(W);             // 0-8  (x dead)
  short* Olo  = (short*)(W + 8 * MB);    // 8-16

  split_x_kernel<<<2048, 256, 0, stream>>>(x, xhi, xlo);
  build_wct_split<<<4096, 256, 0, stream>>>(sr_w, WcThi, WcTlo);
  gemm_x3<true><<<dim3(16, 4, 4), 256, 0, stream>>>(
      xhi, xlo, WcThi, WcTlo, sr_b, Cbuf, 2048, 512, 512, 2048, 512);
  ln_split_kernel<<<2048, 256, 0, stream>>>(Cbuf, ln_g, ln_b, LNhi, LNlo);
  transpose_split_kernel<<<dim3(32, 16), 256, 0, stream>>>(kv_w, wThi, wTlo, 512, 1024);
  gemm_x3<false><<<dim3(16, 8, 2), 256, 0, stream>>>(
      LNhi, LNlo, wThi, wTlo, kv_b, KVp, 2048, 1024, 512, 512, 256);
  build_k_split<<<4096, 256, 0, stream>>>(KVp, KVp + (size_t)2 * MB, Khi, Klo);
  build_vt_kernel<<<4096, 256, 0, stream>>>(KVp, KVp + (size_t)2 * MB, VTb);
  transpose_split_kernel<<<dim3(16, 16), 256, 0, stream>>>(q_w, wThi, wTlo, 512, 512);
  gemm_x3<false><<<dim3(64, 4, 1), 256, 0, stream>>>(
      xhi, xlo, wThi, wTlo, q_b, Qbuf, 8192, 512, 512, 512, 512);
  attn_kernel<<<dim3(16, 8, 8), 256, 0, stream>>>(Qbuf, Khi, Klo, VTb, Ohi, Olo);
  transpose_split_kernel<<<dim3(16, 16), 256, 0, stream>>>(proj_w, wThi, wTlo, 512, 512);
  gemm_x3<false><<<dim3(64, 4, 1), 256, 0, stream>>>(
      Ohi, Olo, wThi, wTlo, proj_b, (float*)d_out, 8192, 512, 512, 512, 512);
}

// Round 4
// 326.295 us; speedup vs baseline: 1.6005x; 1.6005x over previous
//
#include <hip/hip_runtime.h>
#include <stdint.h>

typedef __attribute__((ext_vector_type(8))) short short8;
typedef __attribute__((ext_vector_type(4))) float f32x4;

#define MFMA(A, B, C) __builtin_amdgcn_mfma_f32_16x16x32_bf16(A, B, C, 0, 0, 0)

__device__ inline void split_trunc(float f, short& hi, short& lo) {
  uint32_t u = __float_as_uint(f);
  hi = (short)(u >> 16);
  float r = f - __uint_as_float(u & 0xffff0000u);
  lo = (short)(__float_as_uint(r) >> 16);
}

__device__ inline void gload16(const short* g, short* l) {
  __builtin_amdgcn_global_load_lds(
      (const __attribute__((address_space(1))) void*)g,
      (__attribute__((address_space(3))) void*)l, 16, 0, 0);
}

// ---------- prep kernels ----------

__global__ void split_x_kernel(const float* __restrict__ x, short* __restrict__ hi,
                               short* __restrict__ lo) {
  int t = blockIdx.x * 256 + threadIdx.x;
  float4 v0 = *(const float4*)&x[(size_t)t * 8];
  float4 v1 = *(const float4*)&x[(size_t)t * 8 + 4];
  float buf[8] = {v0.x, v0.y, v0.z, v0.w, v1.x, v1.y, v1.z, v1.w};
  short8 h, l;
#pragma unroll
  for (int i = 0; i < 8; ++i) { short a, b; split_trunc(buf[i], a, b); h[i] = a; l[i] = b; }
  *(short8*)&hi[(size_t)t * 8] = h;
  *(short8*)&lo[(size_t)t * 8] = l;
}

__global__ void build_wct_split(const float* __restrict__ sr_w,
                                short* __restrict__ hi, short* __restrict__ lo) {
  int t = blockIdx.x * 256 + threadIdx.x;
  int kk = t & 2047, o = t >> 11;
  float v = sr_w[(size_t)o * 2048 + ((kk & 511) << 2) + (kk >> 9)];
  short a, b; split_trunc(v, a, b);
  hi[t] = a; lo[t] = b;
}

__global__ __launch_bounds__(256) void transpose_split_kernel(
    const float* __restrict__ in, short* __restrict__ ohi, short* __restrict__ olo,
    int K, int N) {
  __shared__ float tile[32][33];
  const int bx = blockIdx.x, by = blockIdx.y;
  const int tx = threadIdx.x & 31, ty = threadIdx.x >> 5;
#pragma unroll
  for (int i = 0; i < 4; ++i)
    tile[ty + i * 8][tx] = in[(size_t)(by * 32 + ty + i * 8) * N + bx * 32 + tx];
  __syncthreads();
#pragma unroll
  for (int i = 0; i < 4; ++i) {
    int n = bx * 32 + ty + i * 8;
    float v = tile[tx][ty + i * 8];
    short a, b; split_trunc(v, a, b);
    size_t idx = (size_t)n * K + by * 32 + tx;
    ohi[idx] = a; olo[idx] = b;
  }
}

__global__ __launch_bounds__(256) void ln_split_kernel(
    const float* __restrict__ X, const float* __restrict__ g,
    const float* __restrict__ bta, short* __restrict__ hi, short* __restrict__ lo) {
  const int row = blockIdx.x, t = threadIdx.x;
  size_t idx = (size_t)row * 512 + t * 2;
  const size_t PS = (size_t)2048 * 512;
  float2 a0 = *(const float2*)&X[idx];
  float2 a1 = *(const float2*)&X[idx + PS];
  float2 a2 = *(const float2*)&X[idx + 2 * PS];
  float2 a3 = *(const float2*)&X[idx + 3 * PS];
  float x0 = a0.x + a1.x + a2.x + a3.x;
  float x1 = a0.y + a1.y + a2.y + a3.y;
  float s = x0 + x1, sq = x0 * x0 + x1 * x1;
#pragma unroll
  for (int off = 1; off < 64; off <<= 1) {
    s += __shfl_xor(s, off);
    sq += __shfl_xor(sq, off);
  }
  __shared__ float rs[4], rq[4];
  int wid = t >> 6;
  if ((t & 63) == 0) { rs[wid] = s; rq[wid] = sq; }
  __syncthreads();
  s = rs[0] + rs[1] + rs[2] + rs[3];
  sq = rq[0] + rq[1] + rq[2] + rq[3];
  float mu = s * (1.f / 512), var = sq * (1.f / 512) - mu * mu;
  float inv = rsqrtf(var + 1e-5f);
  float2 gg = *(const float2*)&g[t * 2], bb = *(const float2*)&bta[t * 2];
  float o0 = (x0 - mu) * inv * gg.x + bb.x;
  float o1 = (x1 - mu) * inv * gg.y + bb.y;
  short h0, l0, h1, l1;
  split_trunc(o0, h0, l0);
  split_trunc(o1, h1, l1);
  *(uint32_t*)&hi[idx] = (uint32_t)(uint16_t)h0 | ((uint32_t)(uint16_t)h1 << 16);
  *(uint32_t*)&lo[idx] = (uint32_t)(uint16_t)l0 | ((uint32_t)(uint16_t)l1 << 16);
}

__global__ void build_k_split(const float* __restrict__ KV1, const float* __restrict__ KV2,
                              short* __restrict__ khi, short* __restrict__ klo) {
  int t = blockIdx.x * 256 + threadIdx.x;
  int b = t >> 17, i = t & 131071;
  size_t idx = ((size_t)b * 256 + (i >> 9)) * 1024 + (i & 511);
  float v = KV1[idx] + KV2[idx];
  short a, c; split_trunc(v, a, c);
  khi[t] = a; klo[t] = c;
}

__global__ void build_vt_kernel(const float* __restrict__ KV1, const float* __restrict__ KV2,
                                short* __restrict__ vt) {
  int t = blockIdx.x * 256 + threadIdx.x;
  int b = t >> 17, i = t & 131071;
  int d = i >> 11, m = i & 2047;
  size_t idx = ((size_t)b * 256 + (m >> 3)) * 1024 + 512 + (m & 7) * 64 + d;
  float v = KV1[idx] + KV2[idx];
  uint32_t u = __float_as_uint(v);
  vt[t] = (short)((u + 0x7FFFu + ((u >> 16) & 1u)) >> 16);
}

// ---------- bf16x3 GEMM: 64x128 tile, 4 waves (each 64x32), gload_lds staging ----------
template <bool GATHER>
__global__ __launch_bounds__(256) void gemm_x3(
    const short* __restrict__ Ahi, const short* __restrict__ Alo,
    const short* __restrict__ BThi, const short* __restrict__ BTlo,
    const float* __restrict__ bias, float* __restrict__ C,
    int M, int N, int lda, int ldb, int klen) {
  __shared__ short ldsA[2][4][64][8];    // [hi/lo][kg][row][8]  8KB
  __shared__ short ldsB[2][4][128][8];   // [hi/lo][kg][col][8] 16KB
  const int tid = threadIdx.x, lane = tid & 63, wave = tid >> 6;
  const int g = lane >> 4, qi = lane & 15;
  const int row0 = blockIdx.x * 64, col0 = blockIdx.y * 128;
  const int kz = blockIdx.z * klen;
  float* Cz = C + (size_t)blockIdx.z * M * N;
  const bool dobias = (blockIdx.z == 0);
  f32x4 acc[4][2] = {};
  const int arow = tid & 63, akg = tid >> 6;        // A staging: 64 rows x 4 kg
  const int bsm = tid & 127, bk2 = (tid >> 7) * 2;  // B staging: 128 cols x 4 kg

  for (int k0 = kz; k0 < kz + klen; k0 += 32) {
    __syncthreads();
    size_t ao;
    if (GATHER) {
      int row = row0 + arow;
      int bi = row >> 8, p = row & 255;
      int col = k0 + akg * 8;
      int seg = col >> 9, cc = col & 511;
      int n = (2 * (p >> 4) + (seg >> 1)) * 32 + 2 * (p & 15) + (seg & 1);
      ao = ((size_t)bi * 1024 + n) * 512 + cc;
    } else {
      ao = (size_t)(row0 + arow) * lda + k0 + akg * 8;
    }
    gload16(&Ahi[ao], &ldsA[0][akg][arow][0]);
    gload16(&Alo[ao], &ldsA[1][akg][arow][0]);
#pragma unroll
    for (int c = 0; c < 2; ++c) {
      size_t bo = (size_t)(col0 + bsm) * ldb + k0 + (bk2 + c) * 8;
      gload16(&BThi[bo], &ldsB[0][bk2 + c][bsm][0]);
      gload16(&BTlo[bo], &ldsB[1][bk2 + c][bsm][0]);
    }
    __syncthreads();
    short8 ah[4], al[4], bh[2], bl[2];
#pragma unroll
    for (int i = 0; i < 4; ++i) {
      ah[i] = *(const short8*)&ldsA[0][g][i * 16 + qi][0];
      al[i] = *(const short8*)&ldsA[1][g][i * 16 + qi][0];
    }
#pragma unroll
    for (int j = 0; j < 2; ++j) {
      bh[j] = *(const short8*)&ldsB[0][g][wave * 32 + j * 16 + qi][0];
      bl[j] = *(const short8*)&ldsB[1][g][wave * 32 + j * 16 + qi][0];
    }
#pragma unroll
    for (int i = 0; i < 4; ++i)
#pragma unroll
      for (int j = 0; j < 2; ++j) {
        acc[i][j] = MFMA(ah[i], bh[j], acc[i][j]);
        acc[i][j] = MFMA(al[i], bh[j], acc[i][j]);
        acc[i][j] = MFMA(ah[i], bl[j], acc[i][j]);
      }
  }
#pragma unroll
  for (int i = 0; i < 4; ++i)
#pragma unroll
    for (int j = 0; j < 2; ++j) {
      int colb = col0 + wave * 32 + j * 16 + qi;
      float bs = dobias ? bias[colb] : 0.f;
#pragma unroll
      for (int r = 0; r < 4; ++r) {
        int row = row0 + i * 16 + g * 4 + r;
        Cz[(size_t)row * N + colb] = acc[i][j][r] + bs;
      }
    }
}

// ---------- MFMA flash attention: K dbuf-LDS (swizzled gload_lds), V reg-prefetch ----------
__global__ __launch_bounds__(256) void attn_kernel(
    const float* __restrict__ Q, const short* __restrict__ Khi,
    const short* __restrict__ Klo, const short* __restrict__ VT,
    short* __restrict__ Ohi, short* __restrict__ Olo) {
  __shared__ short Ks[2][2][4096];   // [dbuf][hi/lo][64 rows x 64 shorts, XOR-swizzled] 32KB
  __shared__ short Ps[4][2][1024];   // per-wave P bounce 16KB
  const int tid = threadIdx.x, lane = tid & 63, wave = tid >> 6;
  const int g = lane >> 4, qi = lane & 15;
  const int h = blockIdx.y, b = blockIdx.z;
  const int n0 = blockIdx.x * 64 + wave * 16;

  short8 qh[2], ql[2];
  {
    const float* Qr = Q + ((size_t)b * 1024 + n0 + qi) * 512 + h * 64;
#pragma unroll
    for (int ks = 0; ks < 2; ++ks) {
      int dg = ks * 4 + g;
      float4 v0 = *(const float4*)(Qr + dg * 8);
      float4 v1 = *(const float4*)(Qr + dg * 8 + 4);
      float buf[8] = {v0.x, v0.y, v0.z, v0.w, v1.x, v1.y, v1.z, v1.w};
#pragma unroll
      for (int j = 0; j < 8; ++j) {
        short a, c; split_trunc(buf[j] * 0.125f, a, c);
        qh[ks][j] = a; ql[ks][j] = c;
      }
    }
  }
  float m_run = 0.f, l_run = 0.f;
  f32x4 oacc[4] = {};
  const short* Kh = Khi + (size_t)b * 2048 * 64;
  const short* Kl = Klo + (size_t)b * 2048 * 64;
  const short* Vb = VT + (size_t)b * 64 * 2048;
  const int swz = (qi & 7) << 1;
  const int srow = tid >> 3, sch = tid & 7;                 // staging map
  const int ssw = (sch * 16) ^ ((srow & 7) << 4);
  const int srow2 = (256 + tid) >> 3, ssw2 = (sch * 16) ^ ((srow2 & 7) << 4);

  // prologue: stage tile 0 into buf 0
  gload16((const short*)((const char*)Kh + (size_t)srow * 128 + ssw), &Ks[0][0][tid * 8]);
  gload16((const short*)((const char*)Kl + (size_t)srow * 128 + ssw), &Ks[0][1][tid * 8]);
  gload16((const short*)((const char*)Kh + (size_t)srow2 * 128 + ssw2), &Ks[0][0][(256 + tid) * 8]);
  gload16((const short*)((const char*)Kl + (size_t)srow2 * 128 + ssw2), &Ks[0][1][(256 + tid) * 8]);
  __syncthreads();
  int bb = 0;

  for (int t = 0; t < 32; ++t) {
    const int m0 = t * 64;
    // stage next K tile into buf^1 (async, drained by end-of-tile barrier)
    if (t < 31) {
      const size_t g1 = (size_t)(m0 + 64 + srow) * 128;
      const size_t g2 = (size_t)(m0 + 64 + srow2) * 128;
      gload16((const short*)((const char*)Kh + g1 + ssw), &Ks[bb ^ 1][0][tid * 8]);
      gload16((const short*)((const char*)Kl + g1 + ssw), &Ks[bb ^ 1][1][tid * 8]);
      gload16((const short*)((const char*)Kh + g2 + ssw2), &Ks[bb ^ 1][0][(256 + tid) * 8]);
      gload16((const short*)((const char*)Kl + g2 + ssw2), &Ks[bb ^ 1][1][(256 + tid) * 8]);
    }
    // V prefetch into regs (consumed at PV, latency hidden under QK+softmax)
    short8 vreg[8];
#pragma unroll
    for (int ks2 = 0; ks2 < 2; ++ks2)
#pragma unroll
      for (int df = 0; df < 4; ++df)
        vreg[ks2 * 4 + df] =
            *(const short8*)&Vb[(size_t)(df * 16 + qi) * 2048 + m0 + ks2 * 32 + g * 8];
    // QK^T swapped (S^T), K frags from swizzled LDS
    f32x4 s[4] = {};
    const int c0 = 8 * (g ^ (qi & 7)), c1 = 8 * ((g + 4) ^ (qi & 7));
#pragma unroll
    for (int mf = 0; mf < 4; ++mf) {
      const int rowb = (mf * 16 + qi) * 64;
      short8 kh0 = *(const short8*)&Ks[bb][0][rowb + c0];
      short8 kl0 = *(const short8*)&Ks[bb][1][rowb + c0];
      short8 kh1 = *(const short8*)&Ks[bb][0][rowb + c1];
      short8 kl1 = *(const short8*)&Ks[bb][1][rowb + c1];
      s[mf] = MFMA(kh0, qh[0], s[mf]);
      s[mf] = MFMA(kl0, qh[0], s[mf]);
      s[mf] = MFMA(kh0, ql[0], s[mf]);
      s[mf] = MFMA(kh1, qh[1], s[mf]);
      s[mf] = MFMA(kl1, qh[1], s[mf]);
      s[mf] = MFMA(kh1, ql[1], s[mf]);
    }
    // defer-max online softmax
    float lmax = s[0][0];
#pragma unroll
    for (int mf = 0; mf < 4; ++mf)
#pragma unroll
      for (int r = 0; r < 4; ++r) lmax = fmaxf(lmax, s[mf][r]);
    if (!__all(lmax <= m_run + 30.f)) {
      float mx = lmax;
#pragma unroll
      for (int off = 1; off < 64; off <<= 1) mx = fmaxf(mx, __shfl_xor(mx, off));
      float cf = __expf(m_run - mx);
      l_run *= cf;
#pragma unroll
      for (int df = 0; df < 4; ++df) oacc[df] *= cf;
      m_run = mx;
    }
    float lsum = 0.f;
#pragma unroll
    for (int mf = 0; mf < 4; ++mf)
#pragma unroll
      for (int r = 0; r < 4; ++r) {
        float p = __expf(s[mf][r] - m_run);
        s[mf][r] = p;
        lsum += p;
      }
    lsum += __shfl_xor(lsum, 16);
    lsum += __shfl_xor(lsum, 32);
    l_run += lsum;
    // pack P hi/lo -> per-wave LDS bounce
#pragma unroll
    for (int mf = 0; mf < 4; ++mf) {
      uint32_t u0 = __float_as_uint(s[mf][0]);
      uint32_t u1 = __float_as_uint(s[mf][1]);
      uint32_t u2 = __float_as_uint(s[mf][2]);
      uint32_t u3 = __float_as_uint(s[mf][3]);
      uint2 hp, lp;
      hp.x = (u0 >> 16) | (u1 & 0xffff0000u);
      hp.y = (u2 >> 16) | (u3 & 0xffff0000u);
      float r0 = s[mf][0] - __uint_as_float(u0 & 0xffff0000u);
      float r1 = s[mf][1] - __uint_as_float(u1 & 0xffff0000u);
      float r2 = s[mf][2] - __uint_as_float(u2 & 0xffff0000u);
      float r3 = s[mf][3] - __uint_as_float(u3 & 0xffff0000u);
      lp.x = (__float_as_uint(r0) >> 16) | (__float_as_uint(r1) & 0xffff0000u);
      lp.y = (__float_as_uint(r2) >> 16) | (__float_as_uint(r3) & 0xffff0000u);
      int uw = ((mf * 4 + g) ^ swz) << 2;
      *(uint2*)&Ps[wave][0][qi * 64 + uw] = hp;
      *(uint2*)&Ps[wave][1][qi * 64 + uw] = lp;
    }
    // PV with prefetched V regs
#pragma unroll
    for (int ks2 = 0; ks2 < 2; ++ks2) {
      int ur = ((ks2 * 8 + g * 2) ^ swz) << 2;
      short8 pa = *(const short8*)&Ps[wave][0][qi * 64 + ur];
      short8 pl = *(const short8*)&Ps[wave][1][qi * 64 + ur];
#pragma unroll
      for (int df = 0; df < 4; ++df) {
        oacc[df] = MFMA(vreg[ks2 * 4 + df], pa, oacc[df]);
        oacc[df] = MFMA(vreg[ks2 * 4 + df], pl, oacc[df]);
      }
    }
    __syncthreads();   // drains next-tile staging + guards buf reuse
    bb ^= 1;
  }
  float linv = 1.f / l_run;
  size_t obase = ((size_t)b * 1024 + n0 + qi) * 512 + h * 64;
#pragma unroll
  for (int df = 0; df < 4; ++df) {
    float o0 = oacc[df][0] * linv, o1 = oacc[df][1] * linv;
    float o2 = oacc[df][2] * linv, o3 = oacc[df][3] * linv;
    uint32_t u0 = __float_as_uint(o0), u1 = __float_as_uint(o1);
    uint32_t u2 = __float_as_uint(o2), u3 = __float_as_uint(o3);
    uint2 hp, lp;
    hp.x = (u0 >> 16) | (u1 & 0xffff0000u);
    hp.y = (u2 >> 16) | (u3 & 0xffff0000u);
    float r0 = o0 - __uint_as_float(u0 & 0xffff0000u);
    float r1 = o1 - __uint_as_float(u1 & 0xffff0000u);
    float r2 = o2 - __uint_as_float(u2 & 0xffff0000u);
    float r3 = o3 - __uint_as_float(u3 & 0xffff0000u);
    lp.x = (__float_as_uint(r0) >> 16) | (__float_as_uint(r1) & 0xffff0000u);
    lp.y = (__float_as_uint(r2) >> 16) | (__float_as_uint(r3) & 0xffff0000u);
    *(uint2*)&Ohi[obase + df * 16 + g * 4] = hp;
    *(uint2*)&Olo[obase + df * 16 + g * 4] = lp;
  }
}

// ---------- launcher ----------
extern "C" void kernel_launch(void* const* d_in, const int* in_sizes, int n_in,
                              void* d_out, int out_size, void* d_ws, size_t ws_size,
                              hipStream_t stream) {
  const float* x      = (const float*)d_in[0];
  const float* q_w    = (const float*)d_in[3];
  const float* q_b    = (const float*)d_in[4];
  const float* kv_w   = (const float*)d_in[5];
  const float* kv_b   = (const float*)d_in[6];
  const float* sr_w   = (const float*)d_in[7];
  const float* sr_b   = (const float*)d_in[8];
  const float* ln_g   = (const float*)d_in[9];
  const float* ln_b   = (const float*)d_in[10];
  const float* proj_w = (const float*)d_in[11];
  const float* proj_b = (const float*)d_in[12];

  char* W = (char*)d_ws;
  const size_t MB = 1024 * 1024;
  short* xhi  = (short*)(W);             // 0-8
  short* xlo  = (short*)(W + 8 * MB);    // 8-16
  short* WcThi = (short*)(W + 16 * MB);  // 16-18
  short* WcTlo = (short*)(W + 18 * MB);  // 18-20
  float* Cbuf = (float*)(W + 20 * MB);   // 20-36 (4 partials x 4MB)
  short* LNhi = (short*)(W + 36 * MB);   // 36-38
  short* LNlo = (short*)(W + 38 * MB);   // 38-40
  short* wThi = (short*)(W + 40 * MB);   // 40-41
  short* wTlo = (short*)(W + 41 * MB);   // 41-42
  float* KVp  = (float*)(W + 20 * MB);   // 20-36 (2 partials x 8MB; Cbuf dead)
  short* Khi  = (short*)(W + 36 * MB);   // 36-38 (LN dead)
  short* Klo  = (short*)(W + 38 * MB);   // 38-40
  short* VTb  = (short*)(W + 16 * MB);   // 16-18 (WcT dead)
  float* Qbuf = (float*)(W + 20 * MB);   // 20-36 (KVp dead)
  short* Ohi  = (short*)(W);             // 0-8  (x dead)
  short* Olo  = (short*)(W + 8 * MB);    // 8-16

  split_x_kernel<<<2048, 256, 0, stream>>>(x, xhi, xlo);
  build_wct_split<<<4096, 256, 0, stream>>>(sr_w, WcThi, WcTlo);
  gemm_x3<true><<<dim3(32, 4, 4), 256, 0, stream>>>(
      xhi, xlo, WcThi, WcTlo, sr_b, Cbuf, 2048, 512, 512, 2048, 512);
  ln_split_kernel<<<2048, 256, 0, stream>>>(Cbuf, ln_g, ln_b, LNhi, LNlo);
  transpose_split_kernel<<<dim3(32, 16), 256, 0, stream>>>(kv_w, wThi, wTlo, 512, 1024);
  gemm_x3<false><<<dim3(32, 8, 2), 256, 0, stream>>>(
      LNhi, LNlo, wThi, wTlo, kv_b, KVp, 2048, 1024, 512, 512, 256);
  build_k_split<<<4096, 256, 0, stream>>>(KVp, KVp + (size_t)2 * MB, Khi, Klo);
  build_vt_kernel<<<4096, 256, 0, stream>>>(KVp, KVp + (size_t)2 * MB, VTb);
  transpose_split_kernel<<<dim3(16, 16), 256, 0, stream>>>(q_w, wThi, wTlo, 512, 512);
  gemm_x3<false><<<dim3(128, 4, 1), 256, 0, stream>>>(
      xhi, xlo, wThi, wTlo, q_b, Qbuf, 8192, 512, 512, 512, 512);
  attn_kernel<<<dim3(16, 8, 8), 256, 0, stream>>>(Qbuf, Khi, Klo, VTb, Ohi, Olo);
  transpose_split_kernel<<<dim3(16, 16), 256, 0, stream>>>(proj_w, wThi, wTlo, 512, 512);
  gemm_x3<false><<<dim3(128, 4, 1), 256, 0, stream>>>(
      Ohi, Olo, wThi, wTlo, proj_b, (float*)d_out, 8192, 512, 512, 512, 512);
}

// Round 5
// 259.071 us; speedup vs baseline: 2.0158x; 1.2595x over previous
//
#include <hip/hip_runtime.h>
#include <stdint.h>

typedef __attribute__((ext_vector_type(8))) short short8;
typedef __attribute__((ext_vector_type(4))) float f32x4;

#define MFMA(A, B, C) __builtin_amdgcn_mfma_f32_16x16x32_bf16(A, B, C, 0, 0, 0)

__device__ inline void split_trunc(float f, short& hi, short& lo) {
  uint32_t u = __float_as_uint(f);
  hi = (short)(u >> 16);
  float r = f - __uint_as_float(u & 0xffff0000u);
  lo = (short)(__float_as_uint(r) >> 16);
}

__device__ inline void gload16(const short* g, short* l) {
  __builtin_amdgcn_global_load_lds(
      (const __attribute__((address_space(1))) void*)g,
      (__attribute__((address_space(3))) void*)l, 16, 0, 0);
}

// ---------- prep kernels ----------

__global__ void split_x_kernel(const float* __restrict__ x, short* __restrict__ hi,
                               short* __restrict__ lo) {
  int t = blockIdx.x * 256 + threadIdx.x;
  float4 v0 = *(const float4*)&x[(size_t)t * 8];
  float4 v1 = *(const float4*)&x[(size_t)t * 8 + 4];
  float buf[8] = {v0.x, v0.y, v0.z, v0.w, v1.x, v1.y, v1.z, v1.w};
  short8 h, l;
#pragma unroll
  for (int i = 0; i < 8; ++i) { short a, b; split_trunc(buf[i], a, b); h[i] = a; l[i] = b; }
  *(short8*)&hi[(size_t)t * 8] = h;
  *(short8*)&lo[(size_t)t * 8] = l;
}

__global__ void build_wct_split(const float* __restrict__ sr_w,
                                short* __restrict__ hi, short* __restrict__ lo) {
  int t = blockIdx.x * 256 + threadIdx.x;
  int kk = t & 2047, o = t >> 11;
  float v = sr_w[(size_t)o * 2048 + ((kk & 511) << 2) + (kk >> 9)];
  short a, b; split_trunc(v, a, b);
  hi[t] = a; lo[t] = b;
}

__global__ __launch_bounds__(256) void transpose_split_kernel(
    const float* __restrict__ in, short* __restrict__ ohi, short* __restrict__ olo,
    int K, int N) {
  __shared__ float tile[32][33];
  const int bx = blockIdx.x, by = blockIdx.y;
  const int tx = threadIdx.x & 31, ty = threadIdx.x >> 5;
#pragma unroll
  for (int i = 0; i < 4; ++i)
    tile[ty + i * 8][tx] = in[(size_t)(by * 32 + ty + i * 8) * N + bx * 32 + tx];
  __syncthreads();
#pragma unroll
  for (int i = 0; i < 4; ++i) {
    int n = bx * 32 + ty + i * 8;
    float v = tile[tx][ty + i * 8];
    short a, b; split_trunc(v, a, b);
    size_t idx = (size_t)n * K + by * 32 + tx;
    ohi[idx] = a; olo[idx] = b;
  }
}

__global__ __launch_bounds__(256) void ln_split_kernel(
    const float* __restrict__ X, const float* __restrict__ g,
    const float* __restrict__ bta, short* __restrict__ hi, short* __restrict__ lo) {
  const int row = blockIdx.x, t = threadIdx.x;
  size_t idx = (size_t)row * 512 + t * 2;
  const size_t PS = (size_t)2048 * 512;
  float2 a0 = *(const float2*)&X[idx];
  float2 a1 = *(const float2*)&X[idx + PS];
  float2 a2 = *(const float2*)&X[idx + 2 * PS];
  float2 a3 = *(const float2*)&X[idx + 3 * PS];
  float x0 = a0.x + a1.x + a2.x + a3.x;
  float x1 = a0.y + a1.y + a2.y + a3.y;
  float s = x0 + x1, sq = x0 * x0 + x1 * x1;
#pragma unroll
  for (int off = 1; off < 64; off <<= 1) {
    s += __shfl_xor(s, off);
    sq += __shfl_xor(sq, off);
  }
  __shared__ float rs[4], rq[4];
  int wid = t >> 6;
  if ((t & 63) == 0) { rs[wid] = s; rq[wid] = sq; }
  __syncthreads();
  s = rs[0] + rs[1] + rs[2] + rs[3];
  sq = rq[0] + rq[1] + rq[2] + rq[3];
  float mu = s * (1.f / 512), var = sq * (1.f / 512) - mu * mu;
  float inv = rsqrtf(var + 1e-5f);
  float2 gg = *(const float2*)&g[t * 2], bb = *(const float2*)&bta[t * 2];
  float o0 = (x0 - mu) * inv * gg.x + bb.x;
  float o1 = (x1 - mu) * inv * gg.y + bb.y;
  short h0, l0, h1, l1;
  split_trunc(o0, h0, l0);
  split_trunc(o1, h1, l1);
  *(uint32_t*)&hi[idx] = (uint32_t)(uint16_t)h0 | ((uint32_t)(uint16_t)h1 << 16);
  *(uint32_t*)&lo[idx] = (uint32_t)(uint16_t)l0 | ((uint32_t)(uint16_t)l1 << 16);
}

__global__ void build_k_split(const float* __restrict__ KV1, const float* __restrict__ KV2,
                              short* __restrict__ khi, short* __restrict__ klo) {
  int t = blockIdx.x * 256 + threadIdx.x;
  int b = t >> 17, i = t & 131071;
  size_t idx = ((size_t)b * 256 + (i >> 9)) * 1024 + (i & 511);
  float v = KV1[idx] + KV2[idx];
  short a, c; split_trunc(v, a, c);
  khi[t] = a; klo[t] = c;
}

__global__ void build_vt_kernel(const float* __restrict__ KV1, const float* __restrict__ KV2,
                                short* __restrict__ vt) {
  int t = blockIdx.x * 256 + threadIdx.x;
  int b = t >> 17, i = t & 131071;
  int d = i >> 11, m = i & 2047;
  size_t idx = ((size_t)b * 256 + (m >> 3)) * 1024 + 512 + (m & 7) * 64 + d;
  float v = KV1[idx] + KV2[idx];
  uint32_t u = __float_as_uint(v);
  vt[t] = (short)((u + 0x7FFFu + ((u >> 16) & 1u)) >> 16);
}

// ---------- bf16x3 GEMM: 64x128 tile, 4 waves, gload_lds staging ----------
// OMODE 0: f32 out (+bias).  OMODE 1: trunc-split bf16 hi/lo out, scaled by oscale.
template <bool GATHER, int OMODE>
__global__ __launch_bounds__(256) void gemm_x3(
    const short* __restrict__ Ahi, const short* __restrict__ Alo,
    const short* __restrict__ BThi, const short* __restrict__ BTlo,
    const float* __restrict__ bias, float* __restrict__ C,
    short* __restrict__ Chi, short* __restrict__ Clo, float oscale,
    int M, int N, int lda, int ldb, int klen) {
  __shared__ short ldsA[2][4][64][8];
  __shared__ short ldsB[2][4][128][8];
  const int tid = threadIdx.x, lane = tid & 63, wave = tid >> 6;
  const int g = lane >> 4, qi = lane & 15;
  const int row0 = blockIdx.x * 64, col0 = blockIdx.y * 128;
  const int kz = blockIdx.z * klen;
  float* Cz = C + (size_t)blockIdx.z * M * N;
  const bool dobias = (blockIdx.z == 0);
  f32x4 acc[4][2] = {};
  const int arow = tid & 63, akg = tid >> 6;
  const int bsm = tid & 127, bk2 = (tid >> 7) * 2;

  for (int k0 = kz; k0 < kz + klen; k0 += 32) {
    __syncthreads();
    size_t ao;
    if (GATHER) {
      int row = row0 + arow;
      int bi = row >> 8, p = row & 255;
      int col = k0 + akg * 8;
      int seg = col >> 9, cc = col & 511;
      int n = (2 * (p >> 4) + (seg >> 1)) * 32 + 2 * (p & 15) + (seg & 1);
      ao = ((size_t)bi * 1024 + n) * 512 + cc;
    } else {
      ao = (size_t)(row0 + arow) * lda + k0 + akg * 8;
    }
    gload16(&Ahi[ao], &ldsA[0][akg][arow][0]);
    gload16(&Alo[ao], &ldsA[1][akg][arow][0]);
#pragma unroll
    for (int c = 0; c < 2; ++c) {
      size_t bo = (size_t)(col0 + bsm) * ldb + k0 + (bk2 + c) * 8;
      gload16(&BThi[bo], &ldsB[0][bk2 + c][bsm][0]);
      gload16(&BTlo[bo], &ldsB[1][bk2 + c][bsm][0]);
    }
    __syncthreads();
    short8 ah[4], al[4], bh[2], bl[2];
#pragma unroll
    for (int i = 0; i < 4; ++i) {
      ah[i] = *(const short8*)&ldsA[0][g][i * 16 + qi][0];
      al[i] = *(const short8*)&ldsA[1][g][i * 16 + qi][0];
    }
#pragma unroll
    for (int j = 0; j < 2; ++j) {
      bh[j] = *(const short8*)&ldsB[0][g][wave * 32 + j * 16 + qi][0];
      bl[j] = *(const short8*)&ldsB[1][g][wave * 32 + j * 16 + qi][0];
    }
#pragma unroll
    for (int i = 0; i < 4; ++i)
#pragma unroll
      for (int j = 0; j < 2; ++j) {
        acc[i][j] = MFMA(ah[i], bh[j], acc[i][j]);
        acc[i][j] = MFMA(al[i], bh[j], acc[i][j]);
        acc[i][j] = MFMA(ah[i], bl[j], acc[i][j]);
      }
  }
#pragma unroll
  for (int i = 0; i < 4; ++i)
#pragma unroll
    for (int j = 0; j < 2; ++j) {
      int colb = col0 + wave * 32 + j * 16 + qi;
      float bs = dobias ? bias[colb] : 0.f;
#pragma unroll
      for (int r = 0; r < 4; ++r) {
        int row = row0 + i * 16 + g * 4 + r;
        if (OMODE == 0) {
          Cz[(size_t)row * N + colb] = acc[i][j][r] + bs;
        } else {
          float v = (acc[i][j][r] + bs) * oscale;
          short hh, ll;
          split_trunc(v, hh, ll);
          Chi[(size_t)row * N + colb] = hh;
          Clo[(size_t)row * N + colb] = ll;
        }
      }
    }
}

// ---------- MFMA flash attention: 32 queries/wave, K dbuf-LDS, V reg-prefetch ----------
__global__ __launch_bounds__(256, 2) void attn_kernel(
    const short* __restrict__ Qhi, const short* __restrict__ Qlo,
    const short* __restrict__ Khi, const short* __restrict__ Klo,
    const short* __restrict__ VT, short* __restrict__ Ohi, short* __restrict__ Olo) {
  __shared__ short Ks[2][2][4096];      // [dbuf][hi/lo][64x64 swizzled] 32KB
  __shared__ short Ps[4][2][2][1024];   // [wave][qc][hi/lo] 32KB
  const int tid = threadIdx.x, lane = tid & 63, wave = tid >> 6;
  const int g = lane >> 4, qi = lane & 15;
  const int h = blockIdx.y, b = blockIdx.z;
  const int n0 = blockIdx.x * 128 + wave * 32;

  // Q frags pre-split/pre-scaled by Q-GEMM epilogue
  short8 qh[2][2], ql[2][2];   // [qc][ks]
#pragma unroll
  for (int qc = 0; qc < 2; ++qc) {
    const size_t qrow = ((size_t)b * 1024 + n0 + qc * 16 + qi) * 512 + h * 64;
#pragma unroll
    for (int ks = 0; ks < 2; ++ks) {
      qh[qc][ks] = *(const short8*)&Qhi[qrow + (ks * 4 + g) * 8];
      ql[qc][ks] = *(const short8*)&Qlo[qrow + (ks * 4 + g) * 8];
    }
  }
  float m_run = 0.f, l_run[2] = {0.f, 0.f};
  f32x4 oacc[2][4] = {};
  const short* Kh = Khi + (size_t)b * 2048 * 64;
  const short* Kl = Klo + (size_t)b * 2048 * 64;
  const short* Vb = VT + (size_t)b * 64 * 2048;
  const int swz = (qi & 7) << 1;
  const int srow = tid >> 3, sch = tid & 7;
  const int ssw = (sch * 16) ^ ((srow & 7) << 4);
  const int srow2 = (256 + tid) >> 3, ssw2 = (sch * 16) ^ ((srow2 & 7) << 4);

  gload16((const short*)((const char*)Kh + (size_t)srow * 128 + ssw), &Ks[0][0][tid * 8]);
  gload16((const short*)((const char*)Kl + (size_t)srow * 128 + ssw), &Ks[0][1][tid * 8]);
  gload16((const short*)((const char*)Kh + (size_t)srow2 * 128 + ssw2), &Ks[0][0][(256 + tid) * 8]);
  gload16((const short*)((const char*)Kl + (size_t)srow2 * 128 + ssw2), &Ks[0][1][(256 + tid) * 8]);
  __syncthreads();
  int bb = 0;

  for (int t = 0; t < 32; ++t) {
    const int m0 = t * 64;
    if (t < 31) {
      const size_t g1 = (size_t)(m0 + 64 + srow) * 128;
      const size_t g2 = (size_t)(m0 + 64 + srow2) * 128;
      gload16((const short*)((const char*)Kh + g1 + ssw), &Ks[bb ^ 1][0][tid * 8]);
      gload16((const short*)((const char*)Kl + g1 + ssw), &Ks[bb ^ 1][1][tid * 8]);
      gload16((const short*)((const char*)Kh + g2 + ssw2), &Ks[bb ^ 1][0][(256 + tid) * 8]);
      gload16((const short*)((const char*)Kl + g2 + ssw2), &Ks[bb ^ 1][1][(256 + tid) * 8]);
    }
    short8 vreg[8];
#pragma unroll
    for (int ks2 = 0; ks2 < 2; ++ks2)
#pragma unroll
      for (int df = 0; df < 4; ++df)
        vreg[ks2 * 4 + df] =
            *(const short8*)&Vb[(size_t)(df * 16 + qi) * 2048 + m0 + ks2 * 32 + g * 8];
    // QK^T swapped (S^T), both q-columns share K frags
    f32x4 s[2][4] = {};
    const int c0 = 8 * (g ^ (qi & 7)), c1 = 8 * ((g + 4) ^ (qi & 7));
#pragma unroll
    for (int mf = 0; mf < 4; ++mf) {
      const int rowb = (mf * 16 + qi) * 64;
      short8 kh0 = *(const short8*)&Ks[bb][0][rowb + c0];
      short8 kl0 = *(const short8*)&Ks[bb][1][rowb + c0];
      short8 kh1 = *(const short8*)&Ks[bb][0][rowb + c1];
      short8 kl1 = *(const short8*)&Ks[bb][1][rowb + c1];
#pragma unroll
      for (int qc = 0; qc < 2; ++qc) {
        s[qc][mf] = MFMA(kh0, qh[qc][0], s[qc][mf]);
        s[qc][mf] = MFMA(kl0, qh[qc][0], s[qc][mf]);
        s[qc][mf] = MFMA(kh0, ql[qc][0], s[qc][mf]);
        s[qc][mf] = MFMA(kh1, qh[qc][1], s[qc][mf]);
        s[qc][mf] = MFMA(kl1, qh[qc][1], s[qc][mf]);
        s[qc][mf] = MFMA(kh1, ql[qc][1], s[qc][mf]);
      }
    }
    // defer-max online softmax (shared m_run)
    float lmax = s[0][0][0];
#pragma unroll
    for (int qc = 0; qc < 2; ++qc)
#pragma unroll
      for (int mf = 0; mf < 4; ++mf)
#pragma unroll
        for (int r = 0; r < 4; ++r) lmax = fmaxf(lmax, s[qc][mf][r]);
    if (!__all(lmax <= m_run + 30.f)) {
      float mx = lmax;
#pragma unroll
      for (int off = 1; off < 64; off <<= 1) mx = fmaxf(mx, __shfl_xor(mx, off));
      float cf = __expf(m_run - mx);
      l_run[0] *= cf; l_run[1] *= cf;
#pragma unroll
      for (int qc = 0; qc < 2; ++qc)
#pragma unroll
        for (int df = 0; df < 4; ++df) oacc[qc][df] *= cf;
      m_run = mx;
    }
#pragma unroll
    for (int qc = 0; qc < 2; ++qc) {
      float lsum = 0.f;
#pragma unroll
      for (int mf = 0; mf < 4; ++mf)
#pragma unroll
        for (int r = 0; r < 4; ++r) {
          float p = __expf(s[qc][mf][r] - m_run);
          s[qc][mf][r] = p;
          lsum += p;
        }
      lsum += __shfl_xor(lsum, 16);
      lsum += __shfl_xor(lsum, 32);
      l_run[qc] += lsum;
    }
    // pack P hi/lo -> per-wave-per-qc LDS bounce, then PV (V regs shared)
#pragma unroll
    for (int qc = 0; qc < 2; ++qc) {
#pragma unroll
      for (int mf = 0; mf < 4; ++mf) {
        uint32_t u0 = __float_as_uint(s[qc][mf][0]);
        uint32_t u1 = __float_as_uint(s[qc][mf][1]);
        uint32_t u2 = __float_as_uint(s[qc][mf][2]);
        uint32_t u3 = __float_as_uint(s[qc][mf][3]);
        uint2 hp, lp;
        hp.x = (u0 >> 16) | (u1 & 0xffff0000u);
        hp.y = (u2 >> 16) | (u3 & 0xffff0000u);
        float r0 = s[qc][mf][0] - __uint_as_float(u0 & 0xffff0000u);
        float r1 = s[qc][mf][1] - __uint_as_float(u1 & 0xffff0000u);
        float r2 = s[qc][mf][2] - __uint_as_float(u2 & 0xffff0000u);
        float r3 = s[qc][mf][3] - __uint_as_float(u3 & 0xffff0000u);
        lp.x = (__float_as_uint(r0) >> 16) | (__float_as_uint(r1) & 0xffff0000u);
        lp.y = (__float_as_uint(r2) >> 16) | (__float_as_uint(r3) & 0xffff0000u);
        int uw = ((mf * 4 + g) ^ swz) << 2;
        *(uint2*)&Ps[wave][qc][0][qi * 64 + uw] = hp;
        *(uint2*)&Ps[wave][qc][1][qi * 64 + uw] = lp;
      }
#pragma unroll
      for (int ks2 = 0; ks2 < 2; ++ks2) {
        int ur = ((ks2 * 8 + g * 2) ^ swz) << 2;
        short8 pa = *(const short8*)&Ps[wave][qc][0][qi * 64 + ur];
        short8 pl = *(const short8*)&Ps[wave][qc][1][qi * 64 + ur];
#pragma unroll
        for (int df = 0; df < 4; ++df) {
          oacc[qc][df] = MFMA(vreg[ks2 * 4 + df], pa, oacc[qc][df]);
          oacc[qc][df] = MFMA(vreg[ks2 * 4 + df], pl, oacc[qc][df]);
        }
      }
    }
    __syncthreads();
    bb ^= 1;
  }
#pragma unroll
  for (int qc = 0; qc < 2; ++qc) {
    float linv = 1.f / l_run[qc];
    size_t obase = ((size_t)b * 1024 + n0 + qc * 16 + qi) * 512 + h * 64;
#pragma unroll
    for (int df = 0; df < 4; ++df) {
      float o0 = oacc[qc][df][0] * linv, o1 = oacc[qc][df][1] * linv;
      float o2 = oacc[qc][df][2] * linv, o3 = oacc[qc][df][3] * linv;
      uint32_t u0 = __float_as_uint(o0), u1 = __float_as_uint(o1);
      uint32_t u2 = __float_as_uint(o2), u3 = __float_as_uint(o3);
      uint2 hp, lp;
      hp.x = (u0 >> 16) | (u1 & 0xffff0000u);
      hp.y = (u2 >> 16) | (u3 & 0xffff0000u);
      float r0 = o0 - __uint_as_float(u0 & 0xffff0000u);
      float r1 = o1 - __uint_as_float(u1 & 0xffff0000u);
      float r2 = o2 - __uint_as_float(u2 & 0xffff0000u);
      float r3 = o3 - __uint_as_float(u3 & 0xffff0000u);
      lp.x = (__float_as_uint(r0) >> 16) | (__float_as_uint(r1) & 0xffff0000u);
      lp.y = (__float_as_uint(r2) >> 16) | (__float_as_uint(r3) & 0xffff0000u);
      *(uint2*)&Ohi[obase + df * 16 + g * 4] = hp;
      *(uint2*)&Olo[obase + df * 16 + g * 4] = lp;
    }
  }
}

// ---------- launcher ----------
extern "C" void kernel_launch(void* const* d_in, const int* in_sizes, int n_in,
                              void* d_out, int out_size, void* d_ws, size_t ws_size,
                              hipStream_t stream) {
  const float* x      = (const float*)d_in[0];
  const float* q_w    = (const float*)d_in[3];
  const float* q_b    = (const float*)d_in[4];
  const float* kv_w   = (const float*)d_in[5];
  const float* kv_b   = (const float*)d_in[6];
  const float* sr_w   = (const float*)d_in[7];
  const float* sr_b   = (const float*)d_in[8];
  const float* ln_g   = (const float*)d_in[9];
  const float* ln_b   = (const float*)d_in[10];
  const float* proj_w = (const float*)d_in[11];
  const float* proj_b = (const float*)d_in[12];

  char* W = (char*)d_ws;
  const size_t MB = 1024 * 1024;
  short* xhi  = (short*)(W);             // 0-8
  short* xlo  = (short*)(W + 8 * MB);    // 8-16
  short* WcThi = (short*)(W + 16 * MB);  // 16-18
  short* WcTlo = (short*)(W + 18 * MB);  // 18-20
  float* Cbuf = (float*)(W + 20 * MB);   // 20-36 (4 partials x 4MB)
  short* LNhi = (short*)(W + 36 * MB);   // 36-38
  short* LNlo = (short*)(W + 38 * MB);   // 38-40
  short* wThi = (short*)(W + 40 * MB);   // 40-41
  short* wTlo = (short*)(W + 41 * MB);   // 41-42
  float* KVp  = (float*)(W + 20 * MB);   // 20-36 (2 partials x 8MB; Cbuf dead)
  short* Khi  = (short*)(W + 36 * MB);   // 36-38 (LN dead)
  short* Klo  = (short*)(W + 38 * MB);   // 38-40
  short* VTb  = (short*)(W + 16 * MB);   // 16-18 (WcT dead)
  short* Qhi  = (short*)(W + 20 * MB);   // 20-28 (KVp dead)
  short* Qlo  = (short*)(W + 28 * MB);   // 28-36
  short* Ohi  = (short*)(W);             // 0-8  (x dead after Q-GEMM)
  short* Olo  = (short*)(W + 8 * MB);    // 8-16

  split_x_kernel<<<2048, 256, 0, stream>>>(x, xhi, xlo);
  build_wct_split<<<4096, 256, 0, stream>>>(sr_w, WcThi, WcTlo);
  gemm_x3<true, 0><<<dim3(32, 4, 4), 256, 0, stream>>>(
      xhi, xlo, WcThi, WcTlo, sr_b, Cbuf, nullptr, nullptr, 1.f,
      2048, 512, 512, 2048, 512);
  ln_split_kernel<<<2048, 256, 0, stream>>>(Cbuf, ln_g, ln_b, LNhi, LNlo);
  transpose_split_kernel<<<dim3(32, 16), 256, 0, stream>>>(kv_w, wThi, wTlo, 512, 1024);
  gemm_x3<false, 0><<<dim3(32, 8, 2), 256, 0, stream>>>(
      LNhi, LNlo, wThi, wTlo, kv_b, KVp, nullptr, nullptr, 1.f,
      2048, 1024, 512, 512, 256);
  build_k_split<<<4096, 256, 0, stream>>>(KVp, KVp + (size_t)2 * MB, Khi, Klo);
  build_vt_kernel<<<4096, 256, 0, stream>>>(KVp, KVp + (size_t)2 * MB, VTb);
  transpose_split_kernel<<<dim3(16, 16), 256, 0, stream>>>(q_w, wThi, wTlo, 512, 512);
  gemm_x3<false, 1><<<dim3(128, 4, 1), 256, 0, stream>>>(
      xhi, xlo, wThi, wTlo, q_b, nullptr, Qhi, Qlo, 0.125f,
      8192, 512, 512, 512, 512);
  attn_kernel<<<dim3(8, 8, 8), 256, 0, stream>>>(Qhi, Qlo, Khi, Klo, VTb, Ohi, Olo);
  transpose_split_kernel<<<dim3(16, 16), 256, 0, stream>>>(proj_w, wThi, wTlo, 512, 512);
  gemm_x3<false, 0><<<dim3(128, 4, 1), 256, 0, stream>>>(
      Ohi, Olo, wThi, wTlo, proj_b, (float*)d_out, nullptr, nullptr, 1.f,
      8192, 512, 512, 512, 512);
}